// Round 1
// baseline (82.365 us; speedup 1.0000x reference)
//
#include <hip/hip_runtime.h>

// SparseInnerProductDecoder: out[e] = sigmoid(dot(z[row[e]], z[col[e]])), d=64.
// 16 lanes per edge, each lane loads float4 (16 lanes x 16B = 256B = one z row,
// fully coalesced). 4 edges per wave64. __shfl_xor tree-reduce within the
// 16-lane group, lane 0 writes the sigmoid.

__global__ __launch_bounds__(256) void sipd_kernel(
    const float* __restrict__ z,
    const int* __restrict__ row,
    const int* __restrict__ col,
    float* __restrict__ out,
    int E)
{
    int tid = blockIdx.x * blockDim.x + threadIdx.x;
    int e = tid >> 4;          // edge index: 16 lanes per edge
    int l = tid & 15;          // lane within edge group
    if (e >= E) return;

    int r = row[e];
    int c = col[e];

    const float4* zr = reinterpret_cast<const float4*>(z + (size_t)r * 64);
    const float4* zc = reinterpret_cast<const float4*>(z + (size_t)c * 64);

    float4 a = zr[l];
    float4 b = zc[l];

    float d = a.x * b.x;
    d = fmaf(a.y, b.y, d);
    d = fmaf(a.z, b.z, d);
    d = fmaf(a.w, b.w, d);

    // reduce across the 16-lane group (groups are aligned within the wave64)
    d += __shfl_xor(d, 1);
    d += __shfl_xor(d, 2);
    d += __shfl_xor(d, 4);
    d += __shfl_xor(d, 8);

    if (l == 0) {
        out[e] = 1.0f / (1.0f + __expf(-d));
    }
}

extern "C" void kernel_launch(void* const* d_in, const int* in_sizes, int n_in,
                              void* d_out, int out_size, void* d_ws, size_t ws_size,
                              hipStream_t stream)
{
    const float* z   = (const float*)d_in[0];
    const int*   ei  = (const int*)d_in[1];   // [2, E] flat: row block then col block
    float*       out = (float*)d_out;

    int E = out_size;                 // 1,250,000
    const int* row = ei;
    const int* col = ei + E;

    const int block = 256;            // 16 edges per block
    const int edgesPerBlock = block / 16;
    int grid = (E + edgesPerBlock - 1) / edgesPerBlock;

    sipd_kernel<<<grid, block, 0, stream>>>(z, row, col, out, E);
}

// Round 2
// 80.832 us; speedup vs baseline: 1.0190x; 1.0190x over previous
//
#include <hip/hip_runtime.h>

// SparseInnerProductDecoder: out[e] = sigmoid(dot(z[row[e]], z[col[e]])), d=64.
// 16 lanes per edge-row (16 x float4 = 256B = one z row, fully coalesced).
// R2 change: each 16-lane group processes 4 edges -> 8 independent float4
// gathers in flight per lane (4x memory-level parallelism vs R1's 2) to cover
// L2/L3-miss latency. After the xor-tree reduce every lane holds all 4 dots;
// lanes 0..3 write 4 contiguous outputs (16B per group).

__global__ __launch_bounds__(256) void sipd_kernel(
    const float* __restrict__ z,
    const int* __restrict__ row,
    const int* __restrict__ col,
    float* __restrict__ out,
    int E)
{
    int tid = blockIdx.x * blockDim.x + threadIdx.x;
    int g = tid >> 4;              // 16-lane group id
    int l = tid & 15;
    long e0 = (long)g * 4;         // 4 edges per group
    if (e0 >= E) return;

    int r[4], c[4];
#pragma unroll
    for (int k = 0; k < 4; ++k) {
        long e = e0 + k;
        if (e >= E) e = E - 1;     // tail: clamp (duplicate work, writes guarded)
        r[k] = row[e];
        c[k] = col[e];
    }

    // Issue all 8 gathers before any use: 8 outstanding 16B loads per lane.
    float4 a0 = reinterpret_cast<const float4*>(z + (size_t)r[0] * 64)[l];
    float4 b0 = reinterpret_cast<const float4*>(z + (size_t)c[0] * 64)[l];
    float4 a1 = reinterpret_cast<const float4*>(z + (size_t)r[1] * 64)[l];
    float4 b1 = reinterpret_cast<const float4*>(z + (size_t)c[1] * 64)[l];
    float4 a2 = reinterpret_cast<const float4*>(z + (size_t)r[2] * 64)[l];
    float4 b2 = reinterpret_cast<const float4*>(z + (size_t)c[2] * 64)[l];
    float4 a3 = reinterpret_cast<const float4*>(z + (size_t)r[3] * 64)[l];
    float4 b3 = reinterpret_cast<const float4*>(z + (size_t)c[3] * 64)[l];

    float d0, d1, d2, d3;
    {
        float t = a0.x * b0.x;
        t = fmaf(a0.y, b0.y, t); t = fmaf(a0.z, b0.z, t); t = fmaf(a0.w, b0.w, t);
        t += __shfl_xor(t, 1); t += __shfl_xor(t, 2);
        t += __shfl_xor(t, 4); t += __shfl_xor(t, 8);
        d0 = t;
    }
    {
        float t = a1.x * b1.x;
        t = fmaf(a1.y, b1.y, t); t = fmaf(a1.z, b1.z, t); t = fmaf(a1.w, b1.w, t);
        t += __shfl_xor(t, 1); t += __shfl_xor(t, 2);
        t += __shfl_xor(t, 4); t += __shfl_xor(t, 8);
        d1 = t;
    }
    {
        float t = a2.x * b2.x;
        t = fmaf(a2.y, b2.y, t); t = fmaf(a2.z, b2.z, t); t = fmaf(a2.w, b2.w, t);
        t += __shfl_xor(t, 1); t += __shfl_xor(t, 2);
        t += __shfl_xor(t, 4); t += __shfl_xor(t, 8);
        d2 = t;
    }
    {
        float t = a3.x * b3.x;
        t = fmaf(a3.y, b3.y, t); t = fmaf(a3.z, b3.z, t); t = fmaf(a3.w, b3.w, t);
        t += __shfl_xor(t, 1); t += __shfl_xor(t, 2);
        t += __shfl_xor(t, 4); t += __shfl_xor(t, 8);
        d3 = t;
    }

    // All lanes now hold d0..d3; lanes 0..3 write 4 contiguous floats.
    if (l < 4) {
        long e = e0 + l;
        if (e < E) {
            float t = d0;                     // static select chain (no runtime
            if (l == 1) t = d1;               //  array index -> stays in VGPRs)
            else if (l == 2) t = d2;
            else if (l == 3) t = d3;
            out[e] = 1.0f / (1.0f + __expf(-t));
        }
    }
}

extern "C" void kernel_launch(void* const* d_in, const int* in_sizes, int n_in,
                              void* d_out, int out_size, void* d_ws, size_t ws_size,
                              hipStream_t stream)
{
    const float* z   = (const float*)d_in[0];
    const int*   ei  = (const int*)d_in[1];   // [2, E] flat: row block then col block
    float*       out = (float*)d_out;

    int E = out_size;                 // 1,250,000
    const int* row = ei;
    const int* col = ei + E;

    const int block = 256;            // 16 groups/block * 4 edges = 64 edges/block
    const int edgesPerBlock = (block / 16) * 4;
    int grid = (E + edgesPerBlock - 1) / edgesPerBlock;

    sipd_kernel<<<grid, block, 0, stream>>>(z, row, col, out, E);
}

// Round 3
// 48.547 us; speedup vs baseline: 1.6966x; 1.6650x over previous
//
#include <hip/hip_runtime.h>

// SparseInnerProductDecoder: out[e] = sigmoid(dot(z[row[e]], z[col[e]])), d=64.
//
// R3: traffic reduction. R1/R2 both pinned at ~3.57 TB/s L2-miss fetch BW
// (z=25.6MB >> 4MB per-XCD L2); MLP was neutral -> BW-ceiling-bound.
// Fix: convert z to fp16 in d_ws once per launch (stream kernel, ~7us),
// then gather 128B rows (8 lanes x 16B) instead of 256B. Halves bottleneck
// bytes AND line-requests, and doubles the L2-resident fraction of z.
// Dot accumulates in f32; fp16 storage error ~<=0.01 on output vs 0.02 thr.

typedef _Float16 half8 __attribute__((ext_vector_type(8)));

__global__ __launch_bounds__(256) void convert_f32_to_f16_kernel(
    const float* __restrict__ z, _Float16* __restrict__ zh, int n /* floats, multiple of 8 */)
{
    int i = blockIdx.x * blockDim.x + threadIdx.x;   // one thread per 8 floats
    if (i * 8 >= n) return;
    const float4* src = reinterpret_cast<const float4*>(z) + (size_t)i * 2;
    float4 f0 = src[0];
    float4 f1 = src[1];
    half8 h;
    h[0] = (_Float16)f0.x; h[1] = (_Float16)f0.y;
    h[2] = (_Float16)f0.z; h[3] = (_Float16)f0.w;
    h[4] = (_Float16)f1.x; h[5] = (_Float16)f1.y;
    h[6] = (_Float16)f1.z; h[7] = (_Float16)f1.w;
    reinterpret_cast<half8*>(zh)[i] = h;
}

// 8 lanes per edge: 8 x 16B = 128B = one fp16 z-row, one L2 line. 8 edges/wave.
__global__ __launch_bounds__(256) void sipd_f16_kernel(
    const _Float16* __restrict__ zh,
    const int* __restrict__ row,
    const int* __restrict__ col,
    float* __restrict__ out,
    int E)
{
    int tid = blockIdx.x * blockDim.x + threadIdx.x;
    int e = tid >> 3;
    int l = tid & 7;
    if (e >= E) return;

    int r = row[e];
    int c = col[e];

    half8 a = reinterpret_cast<const half8*>(zh + (size_t)r * 64)[l];
    half8 b = reinterpret_cast<const half8*>(zh + (size_t)c * 64)[l];

    float t = (float)a[0] * (float)b[0];
#pragma unroll
    for (int i = 1; i < 8; ++i)
        t = fmaf((float)a[i], (float)b[i], t);

    t += __shfl_xor(t, 1);
    t += __shfl_xor(t, 2);
    t += __shfl_xor(t, 4);

    if (l == 0) {
        out[e] = 1.0f / (1.0f + __expf(-t));
    }
}

// Fallback (ws too small): R1 f32 path, 16 lanes/edge.
__global__ __launch_bounds__(256) void sipd_f32_kernel(
    const float* __restrict__ z,
    const int* __restrict__ row,
    const int* __restrict__ col,
    float* __restrict__ out,
    int E)
{
    int tid = blockIdx.x * blockDim.x + threadIdx.x;
    int e = tid >> 4;
    int l = tid & 15;
    if (e >= E) return;
    int r = row[e];
    int c = col[e];
    float4 a = reinterpret_cast<const float4*>(z + (size_t)r * 64)[l];
    float4 b = reinterpret_cast<const float4*>(z + (size_t)c * 64)[l];
    float t = a.x * b.x;
    t = fmaf(a.y, b.y, t); t = fmaf(a.z, b.z, t); t = fmaf(a.w, b.w, t);
    t += __shfl_xor(t, 1); t += __shfl_xor(t, 2);
    t += __shfl_xor(t, 4); t += __shfl_xor(t, 8);
    if (l == 0) out[e] = 1.0f / (1.0f + __expf(-t));
}

extern "C" void kernel_launch(void* const* d_in, const int* in_sizes, int n_in,
                              void* d_out, int out_size, void* d_ws, size_t ws_size,
                              hipStream_t stream)
{
    const float* z   = (const float*)d_in[0];
    const int*   ei  = (const int*)d_in[1];   // [2, E] flat: row block then col block
    float*       out = (float*)d_out;

    int E   = out_size;        // 1,250,000
    int n_z = in_sizes[0];     // 100000 * 64 = 6,400,000 floats
    const int* row = ei;
    const int* col = ei + E;

    size_t zh_bytes = (size_t)n_z * sizeof(_Float16);   // 12.8 MB

    if (ws_size >= zh_bytes) {
        _Float16* zh = (_Float16*)d_ws;

        int nvec = n_z / 8;    // 800,000 threads, one per 16B output
        convert_f32_to_f16_kernel<<<(nvec + 255) / 256, 256, 0, stream>>>(z, zh, n_z);

        const int block = 256;                 // 32 edges per block
        int grid = (E + 31) / 32;
        sipd_f16_kernel<<<grid, block, 0, stream>>>(zh, row, col, out, E);
    } else {
        const int block = 256;                 // 16 edges per block
        int grid = (E + 15) / 16;
        sipd_f32_kernel<<<grid, block, 0, stream>>>(z, row, col, out, E);
    }
}